// Round 1
// baseline (399.305 us; speedup 1.0000x reference)
//
#include <hip/hip_runtime.h>
#include <math.h>

#define BB 16
#define II 1024
#define HH 2048

__device__ __forceinline__ float gumbel_xf(float u) {
    // -log(-log(u + 1e-10) + 1e-10)
    float l1 = __logf(u + 1e-10f);
    return -__logf(-l1 + 1e-10f);
}

// One wave (64 lanes) handles one (b, o) row of length H=2048.
// Block = 256 threads = 4 waves = 4 consecutive b's for one o.
// Block swizzle: n = 32q + 8g + c  ->  o = 8q + c, batch-group g.
// Same-o blocks differ only in g (stride 8 in n) -> same XCD (n%8), L2 reuse of W_hh row.
__global__ __launch_bounds__(256, 4) void reservoir_cell_kernel(
    const float* __restrict__ x_t,        // (B, I)
    const float* __restrict__ h_prev,     // (B, H)
    const float* __restrict__ W_ih_w,     // (H, I)
    const float* __restrict__ W_ih_b,     // (H,)
    const float* __restrict__ W_hh,       // (H, H)
    const float* __restrict__ hh_mask,    // (H, H)
    const float* __restrict__ temperature,// (1,)
    const float* __restrict__ gumbel,     // (B, H, H)
    float* __restrict__ out)              // (B, H)
{
    const int n    = blockIdx.x;               // 0..8191
    const int o    = ((n >> 5) << 3) + (n & 7);// 0..2047
    const int grp  = (n >> 3) & 3;             // 0..3
    const int wave = threadIdx.x >> 6;         // 0..3
    const int lane = threadIdx.x & 63;
    const int b    = (grp << 2) + wave;        // 0..15

    const float tau     = fmaxf(temperature[0], 1e-3f);
    const float inv_tau = 1.0f / tau;

    // ---- input contribution: dot(x_t[b,:], W_ih_w[o,:]) + b[o] ----
    const float4* x4 = (const float4*)(x_t + (size_t)b * II);
    const float4* w4 = (const float4*)(W_ih_w + (size_t)o * II);
    float ic = 0.0f;
    #pragma unroll
    for (int j = 0; j < 4; ++j) {
        float4 xv = x4[j * 64 + lane];
        float4 wv = w4[j * 64 + lane];
        ic += xv.x * wv.x + xv.y * wv.y + xv.z * wv.z + xv.w * wv.w;
    }
    #pragma unroll
    for (int off = 32; off; off >>= 1) ic += __shfl_down(ic, off, 64);
    ic = __shfl(ic, 0, 64) + W_ih_b[o];

    // ---- row pass: z[h] = W_hh[o,h]*mask[o,h]/tau + gumbel_xf(u[b,o,h]) ----
    const float4* g4 = (const float4*)(gumbel + ((size_t)b * HH + o) * HH);
    const float4* h4 = (const float4*)(W_hh   + (size_t)o * HH);
    const float4* m4 = (const float4*)(hh_mask+ (size_t)o * HH);
    const float4* p4 = (const float4*)(h_prev + (size_t)b * HH);

    float4 z[8];
    float m = -INFINITY;
    #pragma unroll
    for (int j = 0; j < 8; ++j) {
        float4 u  = g4[j * 64 + lane];
        float4 w  = h4[j * 64 + lane];
        float4 mk = m4[j * 64 + lane];
        float4 zz;
        zz.x = w.x * mk.x * inv_tau + gumbel_xf(u.x);
        zz.y = w.y * mk.y * inv_tau + gumbel_xf(u.y);
        zz.z = w.z * mk.z * inv_tau + gumbel_xf(u.z);
        zz.w = w.w * mk.w * inv_tau + gumbel_xf(u.w);
        z[j] = zz;
        m = fmaxf(m, fmaxf(fmaxf(zz.x, zz.y), fmaxf(zz.z, zz.w)));
    }
    #pragma unroll
    for (int off = 32; off; off >>= 1) m = fmaxf(m, __shfl_down(m, off, 64));
    m = __shfl(m, 0, 64);

    // ---- weighted softmax accumulation ----
    float s = 0.0f, t = 0.0f;
    #pragma unroll
    for (int j = 0; j < 8; ++j) {
        float4 hv = p4[j * 64 + lane];
        float e;
        e = __expf(z[j].x - m); s += e; t += e * hv.x;
        e = __expf(z[j].y - m); s += e; t += e * hv.y;
        e = __expf(z[j].z - m); s += e; t += e * hv.z;
        e = __expf(z[j].w - m); s += e; t += e * hv.w;
    }
    #pragma unroll
    for (int off = 32; off; off >>= 1) {
        s += __shfl_down(s, off, 64);
        t += __shfl_down(t, off, 64);
    }

    if (lane == 0) {
        out[(size_t)b * HH + o] = tanhf(ic + t / s);
    }
}

extern "C" void kernel_launch(void* const* d_in, const int* in_sizes, int n_in,
                              void* d_out, int out_size, void* d_ws, size_t ws_size,
                              hipStream_t stream) {
    const float* x_t         = (const float*)d_in[0];
    const float* h_prev      = (const float*)d_in[1];
    const float* W_ih_w      = (const float*)d_in[2];
    const float* W_ih_b      = (const float*)d_in[3];
    const float* W_hh        = (const float*)d_in[4];
    const float* hh_mask     = (const float*)d_in[5];
    const float* temperature = (const float*)d_in[6];
    const float* gumbel      = (const float*)d_in[7];
    float* out = (float*)d_out;

    // B*H rows, 1 wave per row, 4 waves per block -> 16*2048/4 = 8192 blocks
    dim3 grid(8192), block(256);
    reservoir_cell_kernel<<<grid, block, 0, stream>>>(
        x_t, h_prev, W_ih_w, W_ih_b, W_hh, hh_mask, temperature, gumbel, out);
}